// Round 3
// baseline (8783.664 us; speedup 1.0000x reference)
//
#include <hip/hip_runtime.h>
#include <hip/hip_bf16.h>

#define N_NODES 10000
#define N_EDGES 100000
#define DEPTH   6
#define E_CHUNK 12500   // prep-only chunking (h1 staging); 8 chunks

typedef __attribute__((ext_vector_type(8))) short short8;
typedef __attribute__((ext_vector_type(4))) float f32x4;
typedef unsigned short u16;

__device__ __forceinline__ float bf2f(u16 u) {
    union { float f; unsigned int i; } v; v.i = ((unsigned int)u) << 16; return v.f;
}
__device__ __forceinline__ u16 f2bf(float f) {
    union { float f; unsigned int i; } v; v.f = f;
    unsigned int x = v.i;
    unsigned int r = (x + 0x7fffu + ((x >> 16) & 1u)) >> 16;
    return (u16)r;
}

// async global->LDS, 16B per lane
__device__ __forceinline__ void gload_lds16(const void* g, void* s) {
    __builtin_amdgcn_global_load_lds((const __attribute__((address_space(1))) void*)g,
                                     (__attribute__((address_space(3))) void*)s, 16, 0, 0);
}

// ---------------- one-time weight prep ----------------
__global__ void k2_transpose_kernel(const float* __restrict__ k2w, u16* __restrict__ k2T) {
    int idx = blockIdx.x * 256 + threadIdx.x;  // 1024*1024
    int n = idx >> 10, k = idx & 1023;
    k2T[idx] = f2bf(k2w[k * 1024 + n]);
}
// GEMM3 column n = o*64+i takes k3w column i*64+o (emits ewT[e][o][i] directly)
__global__ void k3_permT_kernel(const float* __restrict__ k3w, u16* __restrict__ k3pT) {
    int idx = blockIdx.x * 256 + threadIdx.x;  // 4096*1024
    int n = idx >> 10, c = idx & 1023;
    k3pT[idx] = f2bf(k3w[(size_t)c * 4096 + (n & 63) * 64 + (n >> 6)]);
}
__global__ void b3_permute_kernel(const float* __restrict__ b3, float* __restrict__ b3p) {
    int n = blockIdx.x * 256 + threadIdx.x;  // 4096
    if (n >= 4096) return;
    b3p[n] = b3[(n & 63) * 64 + (n >> 6)];
}

// ---------------- degree ----------------
__global__ void deg_kernel(const int* __restrict__ ei, float* __restrict__ deg) {
    int e = blockIdx.x * 256 + threadIdx.x;
    if (e < N_EDGES) atomicAdd(&deg[ei[N_EDGES + e]], 1.0f);
}

// ---------------- layer 1 (per chunk): h1 = relu(ea @ k1 + b1), bf16 ----------------
__global__ void gemm1_kernel(const float* __restrict__ ea, const float* __restrict__ k1w,
                             const float* __restrict__ k1b, u16* __restrict__ h1, int e0) {
    int idx = blockIdx.x * 256 + threadIdx.x;  // E_CHUNK*1024
    int c = idx & 1023;
    int e = (idx >> 10) + e0;
    float acc = k1b[c];
#pragma unroll
    for (int i = 0; i < 6; i++) acc += ea[e * 6 + i] * k1w[i * 1024 + c];
    h1[idx] = f2bf(fmaxf(acc, 0.0f));
}

// ---------------- 128x128-tile bf16 MFMA GEMM, K=1024 (prep only) ----------------
// Round-2 pipelined variant (3 LDS buffers, counted vmcnt, XOR swizzle) - verified.
template <int NOUT, bool RELU>
__global__ __launch_bounds__(256) void gemm128_kernel(
    const u16* __restrict__ A, const u16* __restrict__ BT,
    const float* __restrict__ bias, u16* __restrict__ C, int M) {
    constexpr int K = 1024;
    constexpr int KTILES = 32;
    __shared__ __align__(16) u16 ldsA[3][128 * 32];
    __shared__ __align__(16) u16 ldsB[3][128 * 32];

    const int t = threadIdx.x;
    const int lane = t & 63, w = t >> 6;
    const int wm = w >> 1, wn = w & 1;
    const int fm = lane & 15, q = lane >> 4;
    const int m0 = blockIdx.y * 128;
    const int n0 = blockIdx.x * 128;

    f32x4 acc[4][4];
#pragma unroll
    for (int a = 0; a < 4; a++)
#pragma unroll
        for (int b = 0; b < 4; b++) acc[a][b] = (f32x4){0.f, 0.f, 0.f, 0.f};

    const u16* gA[2]; const u16* gB[2];
    int dL[2];
#pragma unroll
    for (int l = 0; l < 2; l++) {
        int L = l * 256 + t;
        int r = L >> 2;
        int kq = (L & 3) ^ ((r >> 1) & 3);
        int ra = m0 + r; if (ra >= M) ra = M - 1;
        gA[l] = A + (size_t)ra * K + kq * 8;
        gB[l] = BT + (size_t)(n0 + r) * K + kq * 8;
        dL[l] = L * 8;
    }
    const int xq = q ^ ((fm >> 1) & 3);
    const int aB = (wm * 64 + fm) * 32 + xq * 8;
    const int bB = (wn * 64 + fm) * 32 + xq * 8;

#pragma unroll
    for (int tt = 0; tt < 2; tt++) {
#pragma unroll
        for (int l = 0; l < 2; l++) { gload_lds16(gA[l], &ldsA[tt][dL[l]]); gA[l] += 32; }
#pragma unroll
        for (int l = 0; l < 2; l++) { gload_lds16(gB[l], &ldsB[tt][dL[l]]); gB[l] += 32; }
    }
    asm volatile("s_waitcnt vmcnt(4)" ::: "memory");
    __builtin_amdgcn_s_barrier();
    asm volatile("" ::: "memory");

    int cur = 0;
    for (int kt = 0; kt < KTILES; ++kt) {
        const u16* la = ldsA[cur];
        const u16* lb = ldsB[cur];

        short8 af[4], bf[4];
#pragma unroll
        for (int mi = 0; mi < 4; mi++)
            af[mi] = *reinterpret_cast<const short8*>(&la[aB + mi * 512]);
#pragma unroll
        for (int ni = 0; ni < 4; ni++)
            bf[ni] = *reinterpret_cast<const short8*>(&lb[bB + ni * 512]);

        if (kt + 2 < KTILES) {
            int nb = cur + 2; if (nb >= 3) nb -= 3;
#pragma unroll
            for (int l = 0; l < 2; l++) { gload_lds16(gA[l], &ldsA[nb][dL[l]]); gA[l] += 32; }
#pragma unroll
            for (int l = 0; l < 2; l++) { gload_lds16(gB[l], &ldsB[nb][dL[l]]); gB[l] += 32; }
        }

        __builtin_amdgcn_s_setprio(1);
#pragma unroll
        for (int mi = 0; mi < 4; mi++)
#pragma unroll
            for (int ni = 0; ni < 4; ni++)
                acc[mi][ni] = __builtin_amdgcn_mfma_f32_16x16x32_bf16(af[mi], bf[ni], acc[mi][ni], 0, 0, 0);
        __builtin_amdgcn_s_setprio(0);

        if (kt + 2 < KTILES) {
            asm volatile("s_waitcnt vmcnt(4)" ::: "memory");
        } else if (kt + 1 < KTILES) {
            asm volatile("s_waitcnt vmcnt(0)" ::: "memory");
        }
        if (kt + 1 < KTILES) {
            __builtin_amdgcn_s_barrier();
            asm volatile("" ::: "memory");
        }
        cur = cur + 1; if (cur == 3) cur = 0;
    }

#pragma unroll
    for (int mi = 0; mi < 4; mi++) {
#pragma unroll
        for (int ni = 0; ni < 4; ni++) {
            int col = n0 + wn * 64 + ni * 16 + fm;
            float bsv = bias[col];
#pragma unroll
            for (int r = 0; r < 4; r++) {
                int row = m0 + wm * 64 + mi * 16 + q * 4 + r;
                if (row < M) {
                    float v = acc[mi][ni][r] + bsv;
                    if (RELU) v = fmaxf(v, 0.0f);
                    C[(size_t)row * NOUT + col] = f2bf(v);
                }
            }
        }
    }
}

// ---------------- 256x256-tile 8-phase fused GEMM3 + msg + scatter ----------------
// m201 template port: BM=BN=256, BK=64, 8 waves (2M x 4N), per-wave 128x64 out,
// 128 KiB LDS = 2 dbuf x 2 half x 128rows x 64k x (A,B) bf16. 8 phases per
// 2 K-tiles; each phase: {ds_read subtile || stage 1 half-tile -> barrier ->
// setprio(1) 16 MFMA setprio(0) -> barrier}. vmcnt(4) only at phase-3/7
// boundaries (counted; vmcnt(0) only in the last iteration). T2 XOR swizzle:
// 16B slot s holds global k-slot s^(row&7); read side applies the same XOR.
// Quadrant order per K-tile: (miH0,niH0),(miH0,niH1),(miH1,niH1),(miH1,niH0)
// so A-frags are read twice and both B-frag sets stay resident (24 b128/K-tile).
// Epilogue: wave owns o = bx*4+wn; reduces msg[e][o] = sum_i (ew+b)*z[src,i]
// via 16-lane shuffle -> atomicAdd agg.
__global__ __launch_bounds__(512, 2) void fused256_kernel(
    const u16* __restrict__ A, const u16* __restrict__ BT,
    const float* __restrict__ bias, const int* __restrict__ ei,
    const float* __restrict__ z, float* __restrict__ agg) {
    __shared__ __align__(16) u16 ldsA[2 * 2 * 128 * 64];   // 64 KiB
    __shared__ __align__(16) u16 ldsB[2 * 2 * 128 * 64];   // 64 KiB

    const int t = threadIdx.x;
    const int lane = t & 63, w = t >> 6;
    const int wm = w >> 2, wn = w & 3;        // 2M x 4N waves
    const int fm = lane & 15, q = lane >> 4;
    const int m0 = blockIdx.y * 256;          // edge rows
    const int n0 = blockIdx.x * 256;          // cols
    const int M = N_EDGES;

    // staging: per half-tile (128 rows x 64 k), 2 x 16B loads per thread.
    // linear slot L = l*512 + t: row r = L>>3, phys slot sp = L&7 holds
    // global k-slot sp ^ (r&7) (involution; read applies same XOR).
    const u16* pA[2][2]; const u16* pB[2][2];
    int dOff[2];
#pragma unroll
    for (int l = 0; l < 2; l++) {
        int L = l * 512 + t;
        int r = L >> 3, sp = L & 7;
        int kofs = (sp ^ (r & 7)) * 8;
        dOff[l] = L * 8;
#pragma unroll
        for (int h = 0; h < 2; h++) {
            int ra = m0 + h * 128 + r; if (ra >= M) ra = M - 1;  // clamp tail
            pA[h][l] = A + (size_t)ra * 1024 + kofs;
            pB[h][l] = BT + (size_t)(n0 + h * 128 + r) * 1024 + kofs;
        }
    }

#define LDSA(cp, h) (ldsA + ((((cp) * 2 + (h))) << 13))
#define LDSB(cp, h) (ldsB + ((((cp) * 2 + (h))) << 13))
#define STAGE_A(cp, h, kofs) do { \
        gload_lds16(pA[h][0] + (kofs), LDSA(cp, h) + dOff[0]); \
        gload_lds16(pA[h][1] + (kofs), LDSA(cp, h) + dOff[1]); } while (0)
#define STAGE_B(cp, h, kofs) do { \
        gload_lds16(pB[h][0] + (kofs), LDSB(cp, h) + dOff[0]); \
        gload_lds16(pB[h][1] + (kofs), LDSB(cp, h) + dOff[1]); } while (0)
#define BAR() do { __builtin_amdgcn_s_barrier(); asm volatile("" ::: "memory"); } while (0)

    // read-side swizzled 16B-slot offsets (u16 units): slot = (ks*4+q)^(fm&7)
    int sslot[2];
    sslot[0] = ((q) ^ (fm & 7)) * 8;
    sslot[1] = ((4 + q) ^ (fm & 7)) * 8;
    const int bh = wn >> 1;                   // B half = wn>>1
    const int bRow = (wn & 1) * 64 + fm;      // row-in-half base for B

    f32x4 acc[8][4];
#pragma unroll
    for (int a = 0; a < 8; a++)
#pragma unroll
        for (int b = 0; b < 4; b++) acc[a][b] = (f32x4){0.f, 0.f, 0.f, 0.f};

    short8 af[4][2], bf0[2][2], bf1[2][2];

#define READ_A(cp, miB) do { \
        _Pragma("unroll") for (int m2 = 0; m2 < 4; m2++) \
        _Pragma("unroll") for (int ks = 0; ks < 2; ks++) \
            af[m2][ks] = *reinterpret_cast<const short8*>( \
                LDSA(cp, wm) + (((miB) + m2) * 16 + fm) * 64 + sslot[ks]); } while (0)
#define READ_B(cp, reg, niB) do { \
        _Pragma("unroll") for (int n2 = 0; n2 < 2; n2++) \
        _Pragma("unroll") for (int ks = 0; ks < 2; ks++) \
            reg[n2][ks] = *reinterpret_cast<const short8*>( \
                LDSB(cp, bh) + (bRow + ((niB) + n2) * 16) * 64 + sslot[ks]); } while (0)
#define MFMA_Q(miB, reg, niB) do { \
        __builtin_amdgcn_s_setprio(1); \
        _Pragma("unroll") for (int m2 = 0; m2 < 4; m2++) \
        _Pragma("unroll") for (int n2 = 0; n2 < 2; n2++) { \
            acc[(miB) + m2][(niB) + n2] = __builtin_amdgcn_mfma_f32_16x16x32_bf16( \
                af[m2][0], reg[n2][0], acc[(miB) + m2][(niB) + n2], 0, 0, 0); \
            acc[(miB) + m2][(niB) + n2] = __builtin_amdgcn_mfma_f32_16x16x32_bf16( \
                af[m2][1], reg[n2][1], acc[(miB) + m2][(niB) + n2], 0, 0, 0); } \
        __builtin_amdgcn_s_setprio(0); } while (0)

    // ---- prologue: tile0 (A0,A1,B0,B1), tile1 (B0,B1)
    STAGE_A(0, 0, 0); STAGE_A(0, 1, 0); STAGE_B(0, 0, 0); STAGE_B(0, 1, 0);
    STAGE_B(1, 0, 64); STAGE_B(1, 1, 64);
    asm volatile("s_waitcnt vmcnt(4)" ::: "memory");   // tile0 landed
    BAR();

    for (int it = 0; it < 8; ++it) {
        const int kB = it * 128 + 64;    // tile 2it+1
        const int kC = it * 128 + 128;   // tile 2it+2
        const int kD = it * 128 + 192;   // tile 2it+3
        const bool g = (it < 7);
        // P0: quad (miH0,niH0) of tile 2it; stage tile 2it+1 A-h0
        READ_A(0, 0); READ_B(0, bf0, 0);
        STAGE_A(1, 0, kB);
        BAR();
        MFMA_Q(0, bf0, 0);
        BAR();
        // P1: quad (miH0,niH1); stage tile 2it+1 A-h1
        READ_B(0, bf1, 2);
        STAGE_A(1, 1, kB);
        BAR();
        MFMA_Q(0, bf1, 2);
        BAR();
        // P2: quad (miH1,niH1); stage tile 2it+2 B-h0
        READ_A(0, 4);
        if (g) STAGE_B(0, 0, kC);
        BAR();
        MFMA_Q(4, bf1, 2);
        BAR();
        // P3: quad (miH1,niH0); stage tile 2it+2 B-h1; boundary wait
        if (g) STAGE_B(0, 1, kC);
        BAR();
        MFMA_Q(4, bf0, 0);
        if (g) { asm volatile("s_waitcnt vmcnt(4)" ::: "memory"); }
        else   { asm volatile("s_waitcnt vmcnt(0)" ::: "memory"); }
        BAR();
        // P4: quad (miH0,niH0) of tile 2it+1; stage tile 2it+2 A-h0
        READ_A(1, 0); READ_B(1, bf0, 0);
        if (g) STAGE_A(0, 0, kC);
        BAR();
        MFMA_Q(0, bf0, 0);
        BAR();
        // P5: quad (miH0,niH1); stage tile 2it+2 A-h1
        READ_B(1, bf1, 2);
        if (g) STAGE_A(0, 1, kC);
        BAR();
        MFMA_Q(0, bf1, 2);
        BAR();
        // P6: quad (miH1,niH1); stage tile 2it+3 B-h0
        READ_A(1, 4);
        if (g) STAGE_B(1, 0, kD);
        BAR();
        MFMA_Q(4, bf1, 2);
        BAR();
        // P7: quad (miH1,niH0); stage tile 2it+3 B-h1; boundary wait
        if (g) STAGE_B(1, 1, kD);
        BAR();
        MFMA_Q(4, bf0, 0);
        if (g) {
            asm volatile("s_waitcnt vmcnt(4)" ::: "memory");
            BAR();
        }
    }

    // ---- fused epilogue: msg + scatter. wave owns o = bx*4 + wn, i = 0..63
    const int o = (n0 >> 6) + wn;
    float bsv[4];
    int iidx[4];
#pragma unroll
    for (int ni = 0; ni < 4; ni++) {
        bsv[ni] = bias[n0 + wn * 64 + ni * 16 + fm];
        iidx[ni] = ni * 16 + fm;
    }
#pragma unroll
    for (int mi = 0; mi < 8; mi++) {
#pragma unroll
        for (int r = 0; r < 4; r++) {
            int e = m0 + wm * 128 + mi * 16 + q * 4 + r;  // uniform across fm-group
            float partial = 0.f;
            int dst = 0;
            if (e < M) {
                int src = ei[e];
                dst = ei[N_EDGES + e];
                const float* zs = z + (size_t)src * 64;
#pragma unroll
                for (int ni = 0; ni < 4; ni++)
                    partial += (acc[mi][ni][r] + bsv[ni]) * zs[iidx[ni]];
            }
            partial += __shfl_xor(partial, 1);
            partial += __shfl_xor(partial, 2);
            partial += __shfl_xor(partial, 4);
            partial += __shfl_xor(partial, 8);
            if (fm == 0 && e < M) atomicAdd(&agg[(size_t)dst * 64 + o], partial);
        }
    }
#undef LDSA
#undef LDSB
#undef STAGE_A
#undef STAGE_B
#undef BAR
#undef READ_A
#undef READ_B
#undef MFMA_Q
}

// ---------------- z0 = x @ fc1_w + fc1_b ----------------
__global__ void z0_kernel(const float* __restrict__ x, const float* __restrict__ w,
                          const float* __restrict__ b, float* __restrict__ z) {
    int idx = blockIdx.x * 256 + threadIdx.x;  // N*64
    int n = idx >> 6, o = idx & 63;
    z[idx] = x[n] * w[o] + b[o];
}

// ---------------- z_new = relu(agg/deg + z @ root_w + conv_b) ----------------
__global__ __launch_bounds__(256) void update_kernel(const float* __restrict__ zin,
                                                     const float* __restrict__ agg,
                                                     const float* __restrict__ deg,
                                                     const float* __restrict__ rootw,
                                                     const float* __restrict__ convb,
                                                     float* __restrict__ zout) {
    int n = blockIdx.x * 4 + (threadIdx.x >> 6);
    int o = threadIdx.x & 63;
    float r = convb[o];
    const float* zr = zin + (size_t)n * 64;
#pragma unroll 8
    for (int i = 0; i < 64; i++) r += zr[i] * rootw[i * 64 + o];
    float d = deg[n];
    d = d < 1.0f ? 1.0f : d;
    float v = agg[(size_t)n * 64 + o] / d + r;
    zout[(size_t)n * 64 + o] = fmaxf(v, 0.0f);
}

// ---------------- out = z @ fc2_w + fc2_b ----------------
__global__ void final_kernel(const float* __restrict__ z, const float* __restrict__ w,
                             const float* __restrict__ b, float* __restrict__ out) {
    int n = blockIdx.x * 256 + threadIdx.x;
    if (n >= N_NODES) return;
    float acc = b[0];
#pragma unroll 8
    for (int o = 0; o < 64; o++) acc += z[(size_t)n * 64 + o] * w[o];
    out[n] = acc;
}

// ---------------- diagnostic ----------------
__global__ void dbg_kernel(float* __restrict__ out, float val, int n) {
    int i = blockIdx.x * 256 + threadIdx.x;
    if (i < n) out[i] = val;
}

extern "C" void kernel_launch(void* const* d_in, const int* in_sizes, int n_in,
                              void* d_out, int out_size, void* d_ws, size_t ws_size,
                              hipStream_t stream) {
    const float* x     = (const float*)d_in[0];
    const int*   ei    = (const int*)  d_in[1];
    const float* ea    = (const float*)d_in[2];
    const float* fc1w  = (const float*)d_in[3];
    const float* fc1b  = (const float*)d_in[4];
    const float* k1w   = (const float*)d_in[5];
    const float* k1b   = (const float*)d_in[6];
    const float* k2w   = (const float*)d_in[7];
    const float* k2b   = (const float*)d_in[8];
    const float* k3w   = (const float*)d_in[9];
    const float* k3b   = (const float*)d_in[10];
    const float* rootw = (const float*)d_in[11];
    const float* convb = (const float*)d_in[12];
    const float* fc2w  = (const float*)d_in[13];
    const float* fc2b  = (const float*)d_in[14];
    float* out = (float*)d_out;

    const size_t NEED = 249000000;
    if (ws_size < NEED) {
        dbg_kernel<<<(N_NODES + 255) / 256, 256, 0, stream>>>(out, (float)(ws_size >> 20), N_NODES);
        return;
    }

    char* p = (char*)d_ws;
    auto alloc = [&](size_t bytes) {
        char* r = p;
        p += (bytes + 255) & ~(size_t)255;
        return r;
    };
    u16*   h2   = (u16*)  alloc((size_t)N_EDGES * 1024 * 2);   // 204.8 MB (bf16, L3-resident)
    u16*   h1ch = (u16*)  alloc((size_t)E_CHUNK * 1024 * 2);   // 25.6 MB (prep only)
    u16*   k2T  = (u16*)  alloc((size_t)1024 * 1024 * 2);
    u16*   k3pT = (u16*)  alloc((size_t)4096 * 1024 * 2);
    float* b3p  = (float*)alloc(4096 * 4);
    float* zA   = (float*)alloc((size_t)N_NODES * 64 * 4);
    float* zB   = (float*)alloc((size_t)N_NODES * 64 * 4);
    float* agg  = (float*)alloc((size_t)N_NODES * 64 * 4);
    float* deg  = (float*)alloc((size_t)N_NODES * 4);

    hipMemsetAsync(deg, 0, (size_t)N_NODES * 4, stream);

    k2_transpose_kernel<<<(1024 * 1024) / 256, 256, 0, stream>>>(k2w, k2T);
    k3_permT_kernel<<<(4096 * 1024) / 256, 256, 0, stream>>>(k3w, k3pT);
    b3_permute_kernel<<<16, 256, 0, stream>>>(k3b, b3p);
    deg_kernel<<<(N_EDGES + 255) / 256, 256, 0, stream>>>(ei, deg);

    // h2 = relu(relu(ea@k1+b1)@k2+b2), bf16, once (edge_attr depth-invariant)
    for (int e0 = 0; e0 < N_EDGES; e0 += E_CHUNK) {
        gemm1_kernel<<<(E_CHUNK * 1024) / 256, 256, 0, stream>>>(ea, k1w, k1b, h1ch, e0);
        dim3 g2(1024 / 128, (E_CHUNK + 127) / 128);
        gemm128_kernel<1024, true><<<g2, 256, 0, stream>>>(
            h1ch, k2T, k2b, h2 + (size_t)e0 * 1024, E_CHUNK);
    }

    z0_kernel<<<(N_NODES * 64) / 256, 256, 0, stream>>>(x, fc1w, fc1b, zA);

    float* zin = zA;
    float* zout = zB;
    for (int d = 0; d < DEPTH; d++) {
        hipMemsetAsync(agg, 0, (size_t)N_NODES * 64 * 4, stream);
        // fused: ew = h2@k3p (+b3p) and agg[dst] += z[src]@ew, no ew materialization
        dim3 g3(4096 / 256, (N_EDGES + 255) / 256);  // 16 x 391
        fused256_kernel<<<g3, 512, 0, stream>>>(h2, k3pT, b3p, ei, zin, agg);
        update_kernel<<<N_NODES / 4, 256, 0, stream>>>(zin, agg, deg, rootw, convb, zout);
        float* tmp = zin; zin = zout; zout = tmp;
    }

    final_kernel<<<(N_NODES + 255) / 256, 256, 0, stream>>>(zin, fc2w, fc2b, out);
}